// Round 2
// baseline (113.068 us; speedup 1.0000x reference)
//
#include <hip/hip_runtime.h>
#include <hip/hip_bf16.h>

#define NROWS 16384
#define DIM 64
#define BCOLS 256                     // cols per block: B tile = 32 KB LDS -> 3+ blocks/CU
#define BROWS 512                     // rows per block: 8 waves x 64 rows, single pass
#define NCS (NROWS / BCOLS)           // 64 col-splits
#define NRG (NROWS / BROWS)           // 32 row-groups

static constexpr float TAU = 0.28f;
static constexpr float EPS = 1e-8f;
// exp(x/TAU) = exp2(x * EXP2_SCALE); scale folded into A before bf16 cast.
static constexpr float EXP2_SCALE = (float)(1.0 / (0.28 * 0.6931471805599453));
static constexpr float LN2F = 0.69314718055994530942f;

using short8  = __attribute__((ext_vector_type(8))) short;
using f32x4   = __attribute__((ext_vector_type(4))) float;
using ushort4v = __attribute__((ext_vector_type(4))) unsigned short;

typedef __attribute__((address_space(1))) const unsigned char ga_t;
typedef __attribute__((address_space(3))) unsigned char la_t;

// Kernel 1: per-row L2 normalize; emit A = bf16(EXP2_SCALE * u_norm),
// W = bf16(u_norm + i_norm), p[n] = (u_norm . i_norm)/TAU, zero total[n],
// zero d_out. Each 16-lane group owns one row (float4/lane).
__global__ __launch_bounds__(256) void prep_kernel(
    const float* __restrict__ u, const float* __restrict__ v,
    __hip_bfloat16* __restrict__ a_out, __hip_bfloat16* __restrict__ w_out,
    float* __restrict__ p_out, float* __restrict__ total, float* __restrict__ out)
{
    const int lane = threadIdx.x & 63;
    const int wv   = threadIdx.x >> 6;
    const int l15  = lane & 15;
    const int row  = blockIdx.x * 16 + wv * 4 + (lane >> 4);

    const float4 uu = *(const float4*)(u + (size_t)row * DIM + l15 * 4);
    const float4 vv = *(const float4*)(v + (size_t)row * DIM + l15 * 4);

    float su = uu.x * uu.x + uu.y * uu.y + uu.z * uu.z + uu.w * uu.w;
    float si = vv.x * vv.x + vv.y * vv.y + vv.z * vv.z + vv.w * vv.w;
    float sd = uu.x * vv.x + uu.y * vv.y + uu.z * vv.z + uu.w * vv.w;
#pragma unroll
    for (int m = 1; m < 16; m <<= 1) {
        su += __shfl_xor(su, m, 64);
        si += __shfl_xor(si, m, 64);
        sd += __shfl_xor(sd, m, 64);
    }
    const float inv_u = 1.0f / fmaxf(sqrtf(su), 1e-12f);
    const float inv_i = 1.0f / fmaxf(sqrtf(si), 1e-12f);

    alignas(8) __hip_bfloat16 a4[4], w4[4];
    const float un[4] = {uu.x * inv_u, uu.y * inv_u, uu.z * inv_u, uu.w * inv_u};
    const float in[4] = {vv.x * inv_i, vv.y * inv_i, vv.z * inv_i, vv.w * inv_i};
#pragma unroll
    for (int r = 0; r < 4; r++) {
        a4[r] = __float2bfloat16(EXP2_SCALE * un[r]);
        w4[r] = __float2bfloat16(un[r] + in[r]);
    }
    *(ushort4v*)((unsigned short*)a_out + (size_t)row * DIM + l15 * 4) = *(ushort4v*)a4;
    *(ushort4v*)((unsigned short*)w_out + (size_t)row * DIM + l15 * 4) = *(ushort4v*)w4;

    if (l15 == 0) {
        p_out[row] = sd * inv_u * inv_i * (1.0f / TAU);
        total[row] = 0.0f;
    }
    if (blockIdx.x == 0 && threadIdx.x == 0) out[0] = 0.0f;
}

// Kernel 2: fused GEMM + exp + row-sum.
// Occupancy fix vs previous version: B tile halved to 256 cols (32 KB LDS),
// __launch_bounds__(512,6) -> 3 blocks/CU, 6 waves/SIMD (was 2 blocks / 4
// waves, latency-bound: MfmaUtil 29%, VALUBusy 48%, LDS ~21% -- all idle
// half the time). rs=4 kept so LDS-read volume stays at ~10 us/CU, well
// under the ~17 us VALU+trans floor. Grid 2048 blocks = NRG(32) x NCS(64),
// each wave owns 64 rows, single pass, ONE barrier total.
__global__ __launch_bounds__(512, 6) void score_kernel(
    const __hip_bfloat16* __restrict__ A, const __hip_bfloat16* __restrict__ W,
    float* __restrict__ total)
{
    __shared__ alignas(16) ushort blds[BCOLS * DIM];   // 32 KB

    const int tid  = threadIdx.x;
    const int lane = tid & 63;
    const int wv   = tid >> 6;          // 0..7
    const int l15  = lane & 15;
    const int quad = lane >> 4;
    const int cs   = blockIdx.x & (NCS - 1);
    const int rg   = blockIdx.x >> 6;
    const int col0    = cs * BCOLS;
    const int rowbase = rg * BROWS;

    const ushort* Au = (const ushort*)A;
    const ushort* Wu = (const ushort*)W;

    // Stage B: 2048 16-B chunks; physical slot p -> LDS offset p*16,
    // global chunk c = (p&7) ^ (col&7). Coalesced; XOR-swizzled so every
    // ds_read_b128 below is bank-conflict-free.
#pragma unroll
    for (int q = 0; q < 4; q++) {
        const int p = q * 512 + tid;
        const int j = p >> 3;
        const int c = (p & 7) ^ (j & 7);
        const ushort* g = Wu + (size_t)(col0 + j) * DIM + c * 8;
        __builtin_amdgcn_global_load_lds((ga_t*)g, (la_t*)&blds[(size_t)p * 8], 16, 0, 0);
    }
    __syncthreads();

    const int r0 = rowbase + wv * 64;

    // A fragments: rows r0 + rs*16 + l15, k = kk*32 + quad*8 + [0..7]
    short8 af[4][2];
#pragma unroll
    for (int rs = 0; rs < 4; rs++)
#pragma unroll
        for (int kk = 0; kk < 2; kk++)
            af[rs][kk] = *(const short8*)(
                Au + (size_t)(r0 + rs * 16 + l15) * DIM + kk * 32 + quad * 8);

    f32x4 rowsum[4];
#pragma unroll
    for (int rs = 0; rs < 4; rs++) rowsum[rs] = {0.f, 0.f, 0.f, 0.f};

#pragma unroll 4
    for (int ct = 0; ct < BCOLS / 16; ct++) {
        const int jl = ct * 16 + l15;
        const int sw = l15 & 7;     // (jl & 7) == (l15 & 7)
        const short8 b0 = *(const short8*)&blds[(size_t)(jl * 8 + (quad ^ sw)) * 8];
        const short8 b1 = *(const short8*)&blds[(size_t)(jl * 8 + ((4 + quad) ^ sw)) * 8];
#pragma unroll
        for (int rs = 0; rs < 4; rs++) {
            f32x4 acc = {0.f, 0.f, 0.f, 0.f};
            acc = __builtin_amdgcn_mfma_f32_16x16x32_bf16(af[rs][0], b0, acc, 0, 0, 0);
            acc = __builtin_amdgcn_mfma_f32_16x16x32_bf16(af[rs][1], b1, acc, 0, 0, 0);
            f32x4 e;
#pragma unroll
            for (int r = 0; r < 4; r++) e[r] = __builtin_amdgcn_exp2f(acc[r]);
            rowsum[rs] += e;
        }
    }

    // Sum over the 16 columns held by each l15-group.
#pragma unroll
    for (int m = 1; m < 16; m <<= 1)
#pragma unroll
        for (int rs = 0; rs < 4; rs++)
#pragma unroll
            for (int r = 0; r < 4; r++)
                rowsum[rs][r] += __shfl_xor(rowsum[rs][r], m, 64);

    if (l15 == 0) {
#pragma unroll
        for (int rs = 0; rs < 4; rs++)
#pragma unroll
            for (int r = 0; r < 4; r++)
                atomicAdd(&total[r0 + rs * 16 + quad * 4 + r], rowsum[rs][r]);
    }
}

// Kernel 3: out += mean(log(total + EPS) - p), parallel over 64 blocks.
__global__ __launch_bounds__(256) void finalize_kernel(
    const float* __restrict__ total, const float* __restrict__ p,
    float* __restrict__ out)
{
    __shared__ float red[4];
    const int idx = blockIdx.x * 256 + threadIdx.x;
    float s = __log2f(total[idx] + EPS) * LN2F - p[idx];
#pragma unroll
    for (int m = 1; m < 64; m <<= 1) s += __shfl_xor(s, m, 64);
    if ((threadIdx.x & 63) == 0) red[threadIdx.x >> 6] = s;
    __syncthreads();
    if (threadIdx.x == 0)
        atomicAdd(out, (red[0] + red[1] + red[2] + red[3]) * (1.0f / (float)NROWS));
}

extern "C" void kernel_launch(void* const* d_in, const int* in_sizes, int n_in,
                              void* d_out, int out_size, void* d_ws, size_t ws_size,
                              hipStream_t stream) {
    const float* u = (const float*)d_in[0];
    const float* v = (const float*)d_in[1];

    char* ws = (char*)d_ws;
    __hip_bfloat16* a = (__hip_bfloat16*)(ws);                                  // 2 MB
    __hip_bfloat16* w = (__hip_bfloat16*)(ws + (size_t)NROWS * DIM * 2);        // 2 MB
    float* p   = (float*)(ws + (size_t)NROWS * DIM * 4);                        // 64 KB
    float* tot = (float*)(ws + (size_t)NROWS * DIM * 4 + (size_t)NROWS * 4);    // 64 KB

    prep_kernel<<<NROWS / 16, 256, 0, stream>>>(u, v, a, w, p, tot, (float*)d_out);
    score_kernel<<<NRG * NCS, 512, 0, stream>>>(a, w, tot);
    finalize_kernel<<<NROWS / 256, 256, 0, stream>>>(tot, p, (float*)d_out);
}

// Round 4
// 103.123 us; speedup vs baseline: 1.0964x; 1.0964x over previous
//
#include <hip/hip_runtime.h>
#include <hip/hip_bf16.h>

#define NROWS 16384
#define DIM 64
#define BCOLS 512                     // cols per block: B tile = 64 KB LDS, staged ONCE
#define BROWS 1024                    // rows per block
#define NCS (NROWS / BCOLS)           // 32 col-splits
#define NRG (NROWS / BROWS)           // 16 row-groups

static constexpr float TAU = 0.28f;
static constexpr float EPS = 1e-8f;
// exp(x/TAU) = exp2(x * log2e / TAU). We ALSO fold 2^23 in, so the MFMA
// accumulator directly produces the Schraudolph integer argument:
//   exp2(x) ~= bitcast_f32( (int)(x * 2^23) + EXPB )
// EXPB = (127 - c)*2^23 with c = log2(E[(1+f)2^-f]) = 0.05753 chosen so the
// mean multiplicative error over uniform mantissa fraction is 1.0 (per-term
// +-3%, averages out across the 16384-term row sum; loss error ~1e-3 vs
// threshold 0.199).
static constexpr float EXP2_SCALE = (float)(8388608.0 / (0.28 * 0.6931471805599453));
static constexpr int   EXPB = 1064870600;
static constexpr float LN2F = 0.69314718055994530942f;

using short8   = __attribute__((ext_vector_type(8))) short;
using f32x4    = __attribute__((ext_vector_type(4))) float;
using ushort4v = __attribute__((ext_vector_type(4))) unsigned short;

typedef __attribute__((address_space(1))) const unsigned char ga_t;
typedef __attribute__((address_space(3))) unsigned char la_t;

// Kernel 1: per-row L2 normalize; emit A = bf16(EXP2_SCALE * u_norm),
// W = bf16(u_norm + i_norm), p[n] = (u_norm . i_norm)/TAU, zero total[n],
// zero d_out. Each 16-lane group owns one row (float4/lane).
__global__ __launch_bounds__(256) void prep_kernel(
    const float* __restrict__ u, const float* __restrict__ v,
    __hip_bfloat16* __restrict__ a_out, __hip_bfloat16* __restrict__ w_out,
    float* __restrict__ p_out, float* __restrict__ total, float* __restrict__ out)
{
    const int lane = threadIdx.x & 63;
    const int wv   = threadIdx.x >> 6;
    const int l15  = lane & 15;
    const int row  = blockIdx.x * 16 + wv * 4 + (lane >> 4);

    const float4 uu = *(const float4*)(u + (size_t)row * DIM + l15 * 4);
    const float4 vv = *(const float4*)(v + (size_t)row * DIM + l15 * 4);

    float su = uu.x * uu.x + uu.y * uu.y + uu.z * uu.z + uu.w * uu.w;
    float si = vv.x * vv.x + vv.y * vv.y + vv.z * vv.z + vv.w * vv.w;
    float sd = uu.x * vv.x + uu.y * vv.y + uu.z * vv.z + uu.w * vv.w;
#pragma unroll
    for (int m = 1; m < 16; m <<= 1) {
        su += __shfl_xor(su, m, 64);
        si += __shfl_xor(si, m, 64);
        sd += __shfl_xor(sd, m, 64);
    }
    const float inv_u = 1.0f / fmaxf(sqrtf(su), 1e-12f);
    const float inv_i = 1.0f / fmaxf(sqrtf(si), 1e-12f);

    alignas(8) __hip_bfloat16 a4[4], w4[4];
    const float un[4] = {uu.x * inv_u, uu.y * inv_u, uu.z * inv_u, uu.w * inv_u};
    const float in[4] = {vv.x * inv_i, vv.y * inv_i, vv.z * inv_i, vv.w * inv_i};
#pragma unroll
    for (int r = 0; r < 4; r++) {
        a4[r] = __float2bfloat16(EXP2_SCALE * un[r]);
        w4[r] = __float2bfloat16(un[r] + in[r]);
    }
    *(ushort4v*)((unsigned short*)a_out + (size_t)row * DIM + l15 * 4) = *(ushort4v*)a4;
    *(ushort4v*)((unsigned short*)w_out + (size_t)row * DIM + l15 * 4) = *(ushort4v*)w4;

    if (l15 == 0) {
        p_out[row] = sd * inv_u * inv_i * (1.0f / TAU);
        total[row] = 0.0f;
    }
    if (blockIdx.x == 0 && threadIdx.x == 0) out[0] = 0.0f;
}

// Kernel 2: fused GEMM + Schraudolph-exp + row-sum.
// Geometry = R1's proven skeleton (47.9us): 512 blocks = 16 rg x 32 cs,
// 2 blocks/CU, 8 waves x 64 rows x 2 passes, B tile staged ONCE with
// global_load_lds + XOR swizzle, ONE barrier. Change vs R1: the exp2 trans
// op (13.7-27us of trans-pipe occupancy sitting on the mfma->exp->add
// dependency chain) is replaced by cvt_i32 + int-add + bitcast on the main
// VALU pipe; the 2^23 Schraudolph scale is pre-folded into A.
__global__ __launch_bounds__(512, 4) void score_kernel(
    const __hip_bfloat16* __restrict__ A, const __hip_bfloat16* __restrict__ W,
    float* __restrict__ total)
{
    __shared__ alignas(16) ushort blds[BCOLS * DIM];   // exactly 64 KB

    const int tid  = threadIdx.x;
    const int lane = tid & 63;
    const int wv   = tid >> 6;          // 0..7
    const int l15  = lane & 15;
    const int quad = lane >> 4;
    const int cs   = blockIdx.x & (NCS - 1);
    const int rg   = blockIdx.x >> 5;
    const int col0    = cs * BCOLS;
    const int rowbase = rg * BROWS;

    const ushort* Au = (const ushort*)A;
    const ushort* Wu = (const ushort*)W;

    // Stage B: 4096 16-B chunks; physical slot p -> LDS offset p*16,
    // global chunk c = (p&7) ^ (col&7). Coalesced; XOR-swizzled so every
    // ds_read_b128 below is bank-conflict-free.
#pragma unroll
    for (int q = 0; q < 8; q++) {
        const int p = q * 512 + tid;
        const int j = p >> 3;
        const int c = (p & 7) ^ (j & 7);
        const ushort* g = Wu + (size_t)(col0 + j) * DIM + c * 8;
        __builtin_amdgcn_global_load_lds((ga_t*)g, (la_t*)&blds[(size_t)p * 8], 16, 0, 0);
    }
    __syncthreads();

#pragma unroll 1
    for (int si = 0; si < 2; si++) {
        const int r0 = rowbase + si * 512 + wv * 64;

        // A fragments: rows r0 + rs*16 + l15, k = kk*32 + quad*8 + [0..7]
        short8 af[4][2];
#pragma unroll
        for (int rs = 0; rs < 4; rs++)
#pragma unroll
            for (int kk = 0; kk < 2; kk++)
                af[rs][kk] = *(const short8*)(
                    Au + (size_t)(r0 + rs * 16 + l15) * DIM + kk * 32 + quad * 8);

        f32x4 rowsum[4];
#pragma unroll
        for (int rs = 0; rs < 4; rs++) rowsum[rs] = {0.f, 0.f, 0.f, 0.f};

#pragma unroll 4
        for (int ct = 0; ct < BCOLS / 16; ct++) {
            const int jl = ct * 16 + l15;
            const int sw = l15 & 7;     // (jl & 7) == (l15 & 7)
            const short8 b0 = *(const short8*)&blds[(size_t)(jl * 8 + (quad ^ sw)) * 8];
            const short8 b1 = *(const short8*)&blds[(size_t)(jl * 8 + ((4 + quad) ^ sw)) * 8];
#pragma unroll
            for (int rs = 0; rs < 4; rs++) {
                f32x4 acc = {0.f, 0.f, 0.f, 0.f};
                acc = __builtin_amdgcn_mfma_f32_16x16x32_bf16(af[rs][0], b0, acc, 0, 0, 0);
                acc = __builtin_amdgcn_mfma_f32_16x16x32_bf16(af[rs][1], b1, acc, 0, 0, 0);
#pragma unroll
                for (int r = 0; r < 4; r++)
                    rowsum[rs][r] += __int_as_float((int)acc[r] + EXPB);
            }
        }

        // Sum over the 16 columns held by each l15-group.
#pragma unroll
        for (int m = 1; m < 16; m <<= 1)
#pragma unroll
            for (int rs = 0; rs < 4; rs++)
#pragma unroll
                for (int r = 0; r < 4; r++)
                    rowsum[rs][r] += __shfl_xor(rowsum[rs][r], m, 64);

        if (l15 == 0) {
#pragma unroll
            for (int rs = 0; rs < 4; rs++)
#pragma unroll
                for (int r = 0; r < 4; r++)
                    atomicAdd(&total[r0 + rs * 16 + quad * 4 + r], rowsum[rs][r]);
        }
    }
}

// Kernel 3: out += mean(log(total + EPS) - p), parallel over 64 blocks.
__global__ __launch_bounds__(256) void finalize_kernel(
    const float* __restrict__ total, const float* __restrict__ p,
    float* __restrict__ out)
{
    __shared__ float red[4];
    const int idx = blockIdx.x * 256 + threadIdx.x;
    float s = __log2f(total[idx] + EPS) * LN2F - p[idx];
#pragma unroll
    for (int m = 1; m < 64; m <<= 1) s += __shfl_xor(s, m, 64);
    if ((threadIdx.x & 63) == 0) red[threadIdx.x >> 6] = s;
    __syncthreads();
    if (threadIdx.x == 0)
        atomicAdd(out, (red[0] + red[1] + red[2] + red[3]) * (1.0f / (float)NROWS));
}

extern "C" void kernel_launch(void* const* d_in, const int* in_sizes, int n_in,
                              void* d_out, int out_size, void* d_ws, size_t ws_size,
                              hipStream_t stream) {
    const float* u = (const float*)d_in[0];
    const float* v = (const float*)d_in[1];

    char* ws = (char*)d_ws;
    __hip_bfloat16* a = (__hip_bfloat16*)(ws);                                  // 2 MB
    __hip_bfloat16* w = (__hip_bfloat16*)(ws + (size_t)NROWS * DIM * 2);        // 2 MB
    float* p   = (float*)(ws + (size_t)NROWS * DIM * 4);                        // 64 KB
    float* tot = (float*)(ws + (size_t)NROWS * DIM * 4 + (size_t)NROWS * 4);    // 64 KB

    prep_kernel<<<NROWS / 16, 256, 0, stream>>>(u, v, a, w, p, tot, (float*)d_out);
    score_kernel<<<NRG * NCS, 512, 0, stream>>>(a, w, tot);
    finalize_kernel<<<NROWS / 256, 256, 0, stream>>>(tot, p, (float*)d_out);
}